// Round 16
// baseline (130.859 us; speedup 1.0000x reference)
//
#include <hip/hip_runtime.h>

#define GDIM 128
#define GMASK 127
#define NCELLS (GDIM * GDIM * GDIM)
#define INV_CELL 120.0f
#define EPS 1e-9f

#define BDIM 16                    // 8^3-cell blocks per axis
#define NBINS (BDIM * BDIM * BDIM) // 4096
#define SPB 513                    // starts entries per bin (512 cells + end)
#define STCAP 448                  // per-bin capacity (bin ~Binom mean 296, sd 17)
#define NCHUNK 256                 // point chunks (one block each in hist/scatter)
#define FCAP 736                   // fused-stage capacity (10^3-cell region: mean 579, sd 24)

// Dense record (two float4 halves A/B):
//   A = {rx, ry, rz, bitcast(orig_idx)}   (r = pos * INV_CELL)
//   B = {vx, vy, vz, mass}
// aux[slot] = (li << 20) | oi   (li = local cell, oi = orig idx) — written by
// scatter so binperm never re-reads rec (32 MB of strided sectors -> 4 MB).
// Bin b owns physical slots [binPrefix[b], binPrefix[b+1]). binperm computes a
// CANONICAL within-bin order (sorted by local cell, then orig_idx): the sort
// key set is a pure function of the inputs => bitwise deterministic output.
// In fused_pg's staging, records are transformed once:
//   A.z <- fz (z fraction), A.w <- bitcast(oi | cz<<20)   (oi<2^20, cz<128)

// ---------------- pass 1: per-chunk LDS histogram (no global atomics) ----------------
__global__ __launch_bounds__(256) void hist_kernel(const float* __restrict__ pos,
                                                   unsigned short* __restrict__ cnt,
                                                   int n, int chunk) {
    __shared__ unsigned int lh[NBINS];   // 16 KB
    int c = blockIdx.x, t = threadIdx.x;
    for (int j = t; j < NBINS; j += 256) lh[j] = 0;
    __syncthreads();
    int s = c * chunk, e = min(n, s + chunk);
    for (int i = s + t; i < e; i += 256) {
        int bx = (int)(pos[3 * i + 0] * INV_CELL);   // pos >= 0: trunc == floor
        int by = (int)(pos[3 * i + 1] * INV_CELL);
        int bz = (int)(pos[3 * i + 2] * INV_CELL);
        int bin = ((bx >> 3) << 8) | ((by >> 3) << 4) | (bz >> 3);
        atomicAdd(&lh[bin], 1u);
    }
    __syncthreads();
    unsigned short* row = cnt + (size_t)c * NBINS;
    for (int j = t; j < NBINS; j += 256) row[j] = (unsigned short)lh[j];
}

// ---------------- pass 2a: column scan over [NCHUNK][NBINS] ----------------
__global__ __launch_bounds__(256) void scan_cols_kernel(const unsigned short* __restrict__ cnt,
                                                        unsigned short* __restrict__ offs,
                                                        unsigned int* __restrict__ binTotal) {
    int col = blockIdx.x * 256 + threadIdx.x;   // 4096 threads, one column each
    unsigned int acc = 0;
#pragma unroll 8
    for (int r = 0; r < NCHUNK; ++r) {
        unsigned int v = cnt[(size_t)r * NBINS + col];
        offs[(size_t)r * NBINS + col] = (unsigned short)acc;
        acc += v;
    }
    binTotal[col] = acc;
}

// ---------------- pass 2b: exclusive scan over 4096 bin totals ----------------
__global__ __launch_bounds__(256) void scan_bins_kernel(const unsigned int* __restrict__ binTotal,
                                                        unsigned int* __restrict__ binPrefix,
                                                        int n) {
    __shared__ unsigned int sh[256];
    int t = threadIdx.x;
    unsigned int e[16], s = 0;
#pragma unroll
    for (int j = 0; j < 16; ++j) { e[j] = binTotal[t * 16 + j]; s += e[j]; }
    sh[t] = s;
    __syncthreads();
#pragma unroll
    for (int off = 1; off < 256; off <<= 1) {
        unsigned int add = (t >= off) ? sh[t - off] : 0u;
        __syncthreads();
        sh[t] += add;
        __syncthreads();
    }
    unsigned int run = sh[t] - s;
#pragma unroll
    for (int j = 0; j < 16; ++j) { binPrefix[t * 16 + j] = run; run += e[j]; }
    if (t == 255) binPrefix[NBINS] = (unsigned int)n;
}

// ---------------- pass 3: dense scatter (LDS offsets; order canonicalized by binperm) ----------------
__global__ __launch_bounds__(256) void scatter_dense_kernel(const float* __restrict__ pos,
                                                            const float* __restrict__ vel,
                                                            const float* __restrict__ mass,
                                                            const unsigned short* __restrict__ offs,
                                                            const unsigned int* __restrict__ binPrefix,
                                                            float4* __restrict__ rec,
                                                            unsigned int* __restrict__ aux,
                                                            int n, int chunk) {
    __shared__ unsigned int lof[NBINS];   // 16 KB
    int c = blockIdx.x, t = threadIdx.x;
    const unsigned short* row = offs + (size_t)c * NBINS;
    for (int j = t; j < NBINS; j += 256) lof[j] = (unsigned int)row[j] + binPrefix[j];
    __syncthreads();
    int s = c * chunk, e = min(n, s + chunk);
    for (int i = s + t; i < e; i += 256) {
        float rx = pos[3 * i + 0] * INV_CELL;
        float ry = pos[3 * i + 1] * INV_CELL;
        float rz = pos[3 * i + 2] * INV_CELL;
        int bx = (int)rx, by = (int)ry, bz = (int)rz;
        int bin = ((bx >> 3) << 8) | ((by >> 3) << 4) | (bz >> 3);
        int li  = ((bx & 7) << 6) | ((by & 7) << 3) | (bz & 7);
        unsigned int slot = atomicAdd(&lof[bin], 1u);
        size_t b2 = (size_t)slot * 2;
        rec[b2]     = make_float4(rx, ry, rz, __uint_as_float((unsigned int)i));
        rec[b2 + 1] = make_float4(vel[3 * i + 0], vel[3 * i + 1], vel[3 * i + 2], mass[i]);
        aux[slot] = ((unsigned int)li << 20) | (unsigned int)i;
    }
}

// ---------------- per-bin canonical permutation (reads only aux, coalesced) ----------------
__global__ __launch_bounds__(256) void binperm_kernel(const unsigned int* __restrict__ binPrefix,
                                                      const unsigned int* __restrict__ aux,
                                                      unsigned short* __restrict__ perm16,
                                                      unsigned short* __restrict__ bs16) {
    __shared__ unsigned short codeLi[STCAP];   // cell of physical slot k
    __shared__ unsigned int   oiArr[STCAP];    // orig idx of slot k
    __shared__ unsigned short dstA[STCAP];     // provisional slot, then final sorted pos
    __shared__ unsigned short permL[STCAP];    // provisional sorted pos -> k
    __shared__ unsigned int ccount[512];
    __shared__ unsigned int cstart[513];
    __shared__ unsigned int sh[256];

    int bin = blockIdx.x;
    int t = threadIdx.x;
    unsigned int base = binPrefix[bin];
    unsigned int cnt = binPrefix[bin + 1] - base;
    if (cnt > STCAP) cnt = STCAP;            // statistically never (8.8 sigma)
    ccount[t] = 0;
    ccount[t + 256] = 0;
    __syncthreads();

    for (unsigned int k = t; k < cnt; k += 256) {
        unsigned int a = aux[base + k];
        unsigned int li = a >> 20;
        codeLi[k] = (unsigned short)li;
        oiArr[k] = a & 0xFFFFFu;
        dstA[k] = (unsigned short)atomicAdd(&ccount[li], 1u);
    }
    __syncthreads();

    // exclusive scan of ccount[512] -> cstart (counts only => deterministic)
    unsigned int c0 = ccount[2 * t], c1 = ccount[2 * t + 1], s = c0 + c1;
    sh[t] = s;
    __syncthreads();
#pragma unroll
    for (int off = 1; off < 256; off <<= 1) {
        unsigned int add = (t >= off) ? sh[t - off] : 0u;
        __syncthreads();
        sh[t] += add;
        __syncthreads();
    }
    unsigned int pre = sh[t] - s;
    cstart[2 * t] = pre;
    cstart[2 * t + 1] = pre + c0;
    if (t == 255) cstart[512] = cnt;
    __syncthreads();

    // provisional inverse map
    for (unsigned int k = t; k < cnt; k += 256)
        permL[cstart[codeLi[k]] + dstA[k]] = (unsigned short)k;
    __syncthreads();

    // canonical rank within each cell by orig_idx (O(c^2), c ~ Poisson(0.58))
    for (int cell = t; cell < 512; cell += 256) {
        unsigned int c = ccount[cell];
        if (c == 0) continue;
        unsigned int s0 = cstart[cell];
        for (unsigned int a = 0; a < c; ++a) {
            unsigned int ka = permL[s0 + a];
            unsigned int oia = oiArr[ka];
            unsigned int r = 0;
            for (unsigned int b = 0; b < c; ++b)
                r += (oiArr[permL[s0 + b]] < oia) ? 1u : 0u;
            dstA[ka] = (unsigned short)(s0 + r);   // final sorted pos (unique)
        }
    }
    __syncthreads();

    // perm16[base + sorted] = physical local slot; bs16 = per-bin cell starts
    for (unsigned int k = t; k < cnt; k += 256)
        perm16[base + dstA[k]] = (unsigned short)k;
    for (int i = t; i < SPB; i += 256)
        bs16[(size_t)bin * SPB + i] = (unsigned short)cstart[i];
}

// ---------------- FUSED P2G + grid-vel + G2P: one wg per 8^3 block, no global grid ----------------
// Phase 1: RECORD-PARALLEL staging (span tables + binary search — proven form).
//   Transform once: A.z <- fz, A.w <- bits(oi | cz<<20).
// Phase 2: thread = (node column nx,ny ; z-segment of 3 nodes). Flattened
//   4-cell window loop, branchless z-weights, register accumulators; nodes
//   aliased onto lrecB after a barrier (LDS 29.3 KB => 5 wg/CU).
//   Summation order unchanged => deterministic.
// Phase 3: G2P per own cell (cell coords statically known).
__global__ __launch_bounds__(256) void fused_pg_kernel(const float4* __restrict__ rec,
                                                       const unsigned int* __restrict__ binPrefix,
                                                       const unsigned short* __restrict__ perm16,
                                                       const unsigned short* __restrict__ bs16,
                                                       float* __restrict__ out) {
    __shared__ float4 lrecA[FCAP];             // 11776 B
    __shared__ float4 lrecB[FCAP];             // 11776 B (nodes aliased here after phase 2)
    __shared__ unsigned short cst[100 * 11];   // 2200 B: staged start of cell d=k-1 per column
    __shared__ unsigned int   rSort[300];      // global sorted idx of span start
    __shared__ unsigned int   rBase[300];      // binPrefix of span's bin
    __shared__ unsigned short rDst[301];       // staged dst start (monotone)
    __shared__ unsigned int   sh[128];

    int wg = blockIdx.x;
    int Z = wg & 15, Y = (wg >> 4) & 15, X = wg >> 8;
    int t = threadIdx.x;

    // ---- phase 1a: per-column span discovery (threads 0..99) ----
    unsigned int cnt_[10];
    unsigned int sortA = 0, sortB = 0, sortC = 0;
    unsigned int baseA = 0, baseB = 0, baseC = 0;
    unsigned int colTotal = 0;
    if (t < 100) {
        int dxi = t / 10, dyi = t % 10;
        int cgx = 8 * X - 1 + dxi, cgy = 8 * Y - 1 + dyi;
#pragma unroll
        for (int k = 0; k < 10; ++k) cnt_[k] = 0;
        if ((unsigned)cgx < 128u && (unsigned)cgy < 128u) {
            int bX = cgx >> 3, bY = cgy >> 3;
            int li0 = ((cgx & 7) << 6) | ((cgy & 7) << 3);
            if (Z > 0) {   // cell d=-1 lives in bin Z-1 at lz=7
                int nb = (bX << 8) | (bY << 4) | (Z - 1);
                unsigned int bp = binPrefix[nb];
                const unsigned short* p = bs16 + (size_t)nb * SPB + li0 + 7;
                baseA = bp; sortA = bp + p[0];
                cnt_[0] = (unsigned int)p[1] - (unsigned int)p[0];
            }
            {              // cells d=0..7 in bin Z, lz=0..7 contiguous
                int nb = (bX << 8) | (bY << 4) | Z;
                unsigned int bp = binPrefix[nb];
                const unsigned short* p = bs16 + (size_t)nb * SPB + li0;
                unsigned int prev = p[0];
                baseB = bp; sortB = bp + prev;
#pragma unroll
                for (int k = 1; k <= 8; ++k) {
                    unsigned int cur = p[k];
                    cnt_[k] = cur - prev;
                    prev = cur;
                }
            }
            if (Z < 15) {  // cell d=8 in bin Z+1 at lz=0
                int nb = (bX << 8) | (bY << 4) | (Z + 1);
                unsigned int bp = binPrefix[nb];
                const unsigned short* p = bs16 + (size_t)nb * SPB + li0;
                baseC = bp; sortC = bp + p[0];
                cnt_[9] = (unsigned int)p[1] - (unsigned int)p[0];
            }
        }
#pragma unroll
        for (int k = 0; k < 10; ++k) colTotal += cnt_[k];
        sh[t] = colTotal;
    } else if (t < 128) {
        sh[t] = 0;
    }
    __syncthreads();
    for (int off = 1; off < 128; off <<= 1) {
        unsigned int add = 0;
        if (t < 128 && t >= off) add = sh[t - off];
        __syncthreads();
        if (t < 128) sh[t] += add;
        __syncthreads();
    }
    if (t < 100) {
        unsigned int run = sh[t] - colTotal;   // exclusive staged start of this column
        unsigned short c11[11];
#pragma unroll
        for (int k = 0; k < 10; ++k) {
            c11[k] = (unsigned short)min(run, (unsigned)FCAP);
            run += cnt_[k];
        }
        c11[10] = (unsigned short)min(run, (unsigned)FCAP);
#pragma unroll
        for (int k = 0; k < 11; ++k) cst[t * 11 + k] = c11[k];
        int r = t * 3;
        rSort[r]     = sortA;  rBase[r]     = baseA;  rDst[r]     = c11[0];
        rSort[r + 1] = sortB;  rBase[r + 1] = baseB;  rDst[r + 1] = c11[1];
        rSort[r + 2] = sortC;  rBase[r + 2] = baseC;  rDst[r + 2] = c11[9];
        if (t == 99) rDst[300] = c11[10];
    }
    __syncthreads();

    // ---- phase 1b: record-parallel gather via canonical perm + one-time transform ----
    unsigned int total = rDst[300];
    for (unsigned int q = t; q < total; q += 256) {
        int lo = 0, hi = 300;                 // largest r with rDst[r] <= q
        while (hi - lo > 1) {
            int mid = (lo + hi) >> 1;
            if ((unsigned int)rDst[mid] <= q) lo = mid; else hi = mid;
        }
        unsigned int sIdx = rSort[lo] + (q - rDst[lo]);
        size_t phys = (size_t)(rBase[lo] + perm16[sIdx]) * 2;
        float4 A = rec[phys];
        int cz = (int)A.z;                    // trunc == floor (A.z >= 0)
        float fzv = A.z - (float)cz;
        unsigned int oi = __float_as_uint(A.w);
        A.z = fzv;
        A.w = __uint_as_float(oi | ((unsigned int)cz << 20));
        lrecA[q] = A;
        lrecB[q] = rec[phys + 1];
    }
    __syncthreads();

    // ---- phase 2: flattened per-column-window node sums (registers) ----
    float4 A0 = make_float4(0.f, 0.f, 0.f, 0.f);
    float4 A1 = make_float4(0.f, 0.f, 0.f, 0.f);
    float4 A2 = make_float4(0.f, 0.f, 0.f, 0.f);
    int nb = 0;
    bool active = (t < 243);
    if (active) {
        int col9 = t / 3, s = t - 3 * col9;
        int nx = col9 / 9, ny = col9 % 9;
        int zbase = 8 * Z + 3 * s - 1;        // global z of window cell 0 (d=3s-1)
        nb = nx * 81 + ny * 9 + 3 * s;
#pragma unroll
        for (int i = 0; i < 2; ++i) {
            float cgx = (float)(8 * X - 1 + nx + i);
#pragma unroll
            for (int j = 0; j < 2; ++j) {
                float cgy = (float)(8 * Y - 1 + ny + j);
                const unsigned short* cc = cst + ((nx + i) * 10 + (ny + j)) * 11 + 3 * s;
                unsigned int k0 = cc[0], k4 = cc[4];
                for (unsigned int k = k0; k < k4; ++k) {
                    float4 a = lrecA[k];
                    float4 b = lrecB[k];
                    float fx = a.x - cgx, fy = a.y - cgy;
                    float wx = i ? 1.0f - fx : fx;
                    float wy = j ? 1.0f - fy : fy;
                    float fz = a.z;                             // precomputed
                    float omfz = 1.0f - fz;
                    int d = (int)(__float_as_uint(a.w) >> 20) - zbase;   // 0..3
                    float wm = wx * wy * b.w;
                    float wz0 = (d == 0) ? fz : ((d == 1) ? omfz : 0.0f);
                    float wz1 = (d == 1) ? fz : ((d == 2) ? omfz : 0.0f);
                    float wz2 = (d == 2) ? fz : ((d == 3) ? omfz : 0.0f);
                    float w0 = wm * wz0, w1 = wm * wz1, w2 = wm * wz2;
                    A0.x += w0; A0.y += w0 * b.x; A0.z += w0 * b.y; A0.w += w0 * b.z;
                    A1.x += w1; A1.y += w1 * b.x; A1.z += w1 * b.y; A1.w += w1 * b.z;
                    A2.x += w2; A2.y += w2 * b.x; A2.z += w2 * b.y; A2.w += w2 * b.z;
                }
            }
        }
    }
    __syncthreads();   // all lrecB reads complete -> safe to alias nodes onto it

    float* nodeX = (float*)lrecB;          // 729 floats
    float* nodeY = nodeX + 729;
    float* nodeZ = nodeY + 729;            // 8748 B total, fits in lrecB's 11776 B
    if (active) {
        float inv0 = 1.0f / fmaxf(A0.x, EPS);
        nodeX[nb] = A0.y * inv0; nodeY[nb] = A0.z * inv0; nodeZ[nb] = A0.w * inv0;
        float inv1 = 1.0f / fmaxf(A1.x, EPS);
        nodeX[nb + 1] = A1.y * inv1; nodeY[nb + 1] = A1.z * inv1; nodeZ[nb + 1] = A1.w * inv1;
        float inv2 = 1.0f / fmaxf(A2.x, EPS);
        nodeX[nb + 2] = A2.y * inv2; nodeY[nb + 2] = A2.z * inv2; nodeZ[nb + 2] = A2.w * inv2;
    }
    __syncthreads();

    // ---- phase 3: G2P per own cell from LDS nodes (cell coords known) ----
    for (int cell = t; cell < 512; cell += 256) {
        int lx = cell >> 6, ly = (cell >> 3) & 7, lz = cell & 7;
        const unsigned short* cc = cst + ((lx + 1) * 10 + (ly + 1)) * 11 + (lz + 1);
        unsigned int s0 = cc[0], e0 = cc[1];
        float bx = (float)(8 * X + lx), by = (float)(8 * Y + ly);
        int nb3 = lx * 81 + ly * 9 + lz;
        for (unsigned int k = s0; k < e0; ++k) {
            float4 a = lrecA[k];
            float fx = a.x - bx, fy = a.y - by, fz = a.z;   // fz precomputed
            float wxa[2] = {1.0f - fx, fx};
            float wya[2] = {1.0f - fy, fy};
            float wza[2] = {1.0f - fz, fz};
            float ox = 0.f, oy = 0.f, oz = 0.f;
#pragma unroll
            for (int i = 0; i < 2; ++i) {
#pragma unroll
                for (int j = 0; j < 2; ++j) {
#pragma unroll
                    for (int l = 0; l < 2; ++l) {
                        int ni = nb3 + i * 81 + j * 9 + l;
                        float w = wxa[i] * wya[j] * wza[l];
                        ox += w * nodeX[ni];
                        oy += w * nodeY[ni];
                        oz += w * nodeZ[ni];
                    }
                }
            }
            unsigned int oi = __float_as_uint(a.w) & 0xFFFFFu;
            out[3 * (size_t)oi + 0] = ox;
            out[3 * (size_t)oi + 1] = oy;
            out[3 * (size_t)oi + 2] = oz;
        }
    }
}

// ---------------- fallback (atomic path, needs only 32 MiB) ----------------
__global__ __launch_bounds__(256) void p2g_atomic_kernel(const float* __restrict__ pos,
                                                         const float* __restrict__ vel,
                                                         const float* __restrict__ mass,
                                                         float4* __restrict__ grid, int n) {
    int i = blockIdx.x * blockDim.x + threadIdx.x;
    if (i >= n) return;
    float rx = pos[3 * i] * INV_CELL, ry = pos[3 * i + 1] * INV_CELL, rz = pos[3 * i + 2] * INV_CELL;
    int bx = (int)floorf(rx), by = (int)floorf(ry), bz = (int)floorf(rz);
    float wx[2] = {1.0f - (rx - bx), rx - bx}, wy[2] = {1.0f - (ry - by), ry - by}, wz[2] = {1.0f - (rz - bz), rz - bz};
    float m = mass[i], vx = vel[3 * i], vy = vel[3 * i + 1], vz = vel[3 * i + 2];
#pragma unroll
    for (int a = 0; a < 2; ++a)
#pragma unroll
        for (int b = 0; b < 2; ++b)
#pragma unroll
            for (int c = 0; c < 2; ++c) {
                float w = wx[a] * wy[b] * wz[c] * m;
                int idx = (((((bx + a) & GMASK) << 7) | ((by + b) & GMASK)) << 7) | ((bz + c) & GMASK);
                float* cell = (float*)(grid + idx);
                atomicAdd(cell + 0, w);
                atomicAdd(cell + 1, w * vx);
                atomicAdd(cell + 2, w * vy);
                atomicAdd(cell + 3, w * vz);
            }
}

__global__ __launch_bounds__(256) void gridvel_kernel(float4* __restrict__ grid) {
    int i = blockIdx.x * blockDim.x + threadIdx.x;
    if (i >= NCELLS) return;
    float4 g = grid[i];
    float inv = 1.0f / fmaxf(g.x, EPS);
    grid[i] = make_float4(g.y * inv, g.z * inv, g.w * inv, 0.0f);
}

__global__ __launch_bounds__(256) void g2p_plain_kernel(const float* __restrict__ pos,
                                                        const float4* __restrict__ grid,
                                                        float* __restrict__ out, int n) {
    int i = blockIdx.x * blockDim.x + threadIdx.x;
    if (i >= n) return;
    float rx = pos[3 * i] * INV_CELL, ry = pos[3 * i + 1] * INV_CELL, rz = pos[3 * i + 2] * INV_CELL;
    int bx = (int)floorf(rx), by = (int)floorf(ry), bz = (int)floorf(rz);
    float wx[2] = {1.0f - (rx - bx), rx - bx}, wy[2] = {1.0f - (ry - by), ry - by}, wz[2] = {1.0f - (rz - bz), rz - bz};
    float ox = 0, oy = 0, oz = 0;
#pragma unroll
    for (int a = 0; a < 2; ++a)
#pragma unroll
        for (int b = 0; b < 2; ++b)
#pragma unroll
            for (int c = 0; c < 2; ++c) {
                float w = wx[a] * wy[b] * wz[c];
                int idx = (((((bx + a) & GMASK) << 7) | ((by + b) & GMASK)) << 7) | ((bz + c) & GMASK);
                float4 g = grid[idx];
                ox += w * g.x; oy += w * g.y; oz += w * g.z;
            }
    out[3 * i] = ox; out[3 * i + 1] = oy; out[3 * i + 2] = oz;
}

extern "C" void kernel_launch(void* const* d_in, const int* in_sizes, int n_in,
                              void* d_out, int out_size, void* d_ws, size_t ws_size,
                              hipStream_t stream) {
    const float* pos  = (const float*)d_in[0];
    const float* vel  = (const float*)d_in[1];
    const float* mass = (const float*)d_in[2];
    float* out = (float*)d_out;
    int n = in_sizes[2];

    char* ws = (char*)d_ws;
    size_t off = 0;
    float4* rec  = (float4*)(ws + off);                    off += (size_t)n * 32;               // 30.5 MiB
    unsigned int* binTotal  = (unsigned int*)(ws + off);   off += (size_t)NBINS * 4;
    unsigned int* binPrefix = (unsigned int*)(ws + off);   off += (size_t)(NBINS + 8) * 4;
    unsigned int* aux       = (unsigned int*)(ws + off);   off += (size_t)n * 4;                // 4 MiB
    unsigned short* cnt     = (unsigned short*)(ws + off); off += (size_t)NCHUNK * NBINS * 2;   // 2 MiB
    unsigned short* offs    = (unsigned short*)(ws + off); off += (size_t)NCHUNK * NBINS * 2;   // 2 MiB
    unsigned short* bs16    = (unsigned short*)(ws + off); off += (size_t)NBINS * SPB * 2;      // 4.2 MiB
    unsigned short* perm16  = (unsigned short*)(ws + off); off += (size_t)n * 2;                // 2 MiB
    size_t need = off;

    int pblocks = (n + 255) / 256;
    int chunk = (n + NCHUNK - 1) / NCHUNK;

    if (ws_size < need) {
        float4* g0 = (float4*)d_ws;   // fallback path owns the whole workspace
        hipMemsetAsync(d_ws, 0, (size_t)NCELLS * 16, stream);
        p2g_atomic_kernel<<<pblocks, 256, 0, stream>>>(pos, vel, mass, g0, n);
        gridvel_kernel<<<NCELLS / 256, 256, 0, stream>>>(g0);
        g2p_plain_kernel<<<pblocks, 256, 0, stream>>>(pos, g0, out, n);
        return;
    }

    hist_kernel<<<NCHUNK, 256, 0, stream>>>(pos, cnt, n, chunk);
    scan_cols_kernel<<<NBINS / 256, 256, 0, stream>>>(cnt, offs, binTotal);
    scan_bins_kernel<<<1, 256, 0, stream>>>(binTotal, binPrefix, n);
    scatter_dense_kernel<<<NCHUNK, 256, 0, stream>>>(pos, vel, mass, offs, binPrefix, rec, aux, n, chunk);
    binperm_kernel<<<NBINS, 256, 0, stream>>>(binPrefix, aux, perm16, bs16);
    fused_pg_kernel<<<NBINS, 256, 0, stream>>>(rec, binPrefix, perm16, bs16, out);
}

// Round 17
// 120.658 us; speedup vs baseline: 1.0845x; 1.0845x over previous
//
#include <hip/hip_runtime.h>

#define GDIM 128
#define GMASK 127
#define NCELLS (GDIM * GDIM * GDIM)
#define INV_CELL 120.0f
#define EPS 1e-9f

#define BDIM 16                    // 8^3-cell blocks per axis
#define NBINS (BDIM * BDIM * BDIM) // 4096
#define SPB 513                    // starts entries per bin (512 cells + end)
#define STCAP 448                  // per-bin capacity (bin ~Binom mean 296, sd 17)
#define NCHUNK 256                 // point chunks (one block each in hist/scatter)
#define FCAP 736                   // fused-stage capacity (10^3-cell region: mean 579, sd 24)

// Dense record (two float4 halves A/B):
//   A = {rx, ry, rz, bitcast(orig_idx)}   (r = pos * INV_CELL)
//   B = {vx, vy, vz, mass}
// Bin b owns physical slots [binPrefix[b], binPrefix[b+1]). binperm computes a
// CANONICAL within-bin order (sorted by local cell, then orig_idx) WITHOUT
// rewriting rec: perm16[binPrefix[b]+s] = physical local slot of sorted pos s,
// bs16[b*SPB+li] = sorted start of cell li (relative to bin). All downstream
// sums iterate in this canonical order => bitwise deterministic.
// In fused_pg's staging, records are transformed once:
//   A.z <- fz (z fraction), A.w <- bitcast(oi | cz<<20)   (oi<2^20, cz<128)

// ---------------- pass 1: per-chunk LDS histogram (no global atomics) ----------------
__global__ __launch_bounds__(256) void hist_kernel(const float* __restrict__ pos,
                                                   unsigned short* __restrict__ cnt,
                                                   int n, int chunk) {
    __shared__ unsigned int lh[NBINS];   // 16 KB
    int c = blockIdx.x, t = threadIdx.x;
    for (int j = t; j < NBINS; j += 256) lh[j] = 0;
    __syncthreads();
    int s = c * chunk, e = min(n, s + chunk);
    for (int i = s + t; i < e; i += 256) {
        int bx = (int)(pos[3 * i + 0] * INV_CELL);   // pos >= 0: trunc == floor
        int by = (int)(pos[3 * i + 1] * INV_CELL);
        int bz = (int)(pos[3 * i + 2] * INV_CELL);
        int bin = ((bx >> 3) << 8) | ((by >> 3) << 4) | (bz >> 3);
        atomicAdd(&lh[bin], 1u);
    }
    __syncthreads();
    unsigned short* row = cnt + (size_t)c * NBINS;
    for (int j = t; j < NBINS; j += 256) row[j] = (unsigned short)lh[j];
}

// ---------------- pass 2a: column scan over [NCHUNK][NBINS] ----------------
__global__ __launch_bounds__(256) void scan_cols_kernel(const unsigned short* __restrict__ cnt,
                                                        unsigned short* __restrict__ offs,
                                                        unsigned int* __restrict__ binTotal) {
    int col = blockIdx.x * 256 + threadIdx.x;   // 4096 threads, one column each
    unsigned int acc = 0;
#pragma unroll 8
    for (int r = 0; r < NCHUNK; ++r) {
        unsigned int v = cnt[(size_t)r * NBINS + col];
        offs[(size_t)r * NBINS + col] = (unsigned short)acc;
        acc += v;
    }
    binTotal[col] = acc;
}

// ---------------- pass 2b: exclusive scan over 4096 bin totals ----------------
__global__ __launch_bounds__(256) void scan_bins_kernel(const unsigned int* __restrict__ binTotal,
                                                        unsigned int* __restrict__ binPrefix,
                                                        int n) {
    __shared__ unsigned int sh[256];
    int t = threadIdx.x;
    unsigned int e[16], s = 0;
#pragma unroll
    for (int j = 0; j < 16; ++j) { e[j] = binTotal[t * 16 + j]; s += e[j]; }
    sh[t] = s;
    __syncthreads();
#pragma unroll
    for (int off = 1; off < 256; off <<= 1) {
        unsigned int add = (t >= off) ? sh[t - off] : 0u;
        __syncthreads();
        sh[t] += add;
        __syncthreads();
    }
    unsigned int run = sh[t] - s;
#pragma unroll
    for (int j = 0; j < 16; ++j) { binPrefix[t * 16 + j] = run; run += e[j]; }
    if (t == 255) binPrefix[NBINS] = (unsigned int)n;
}

// ---------------- pass 3: dense scatter (LDS offsets; order canonicalized by binperm) ----------------
__global__ __launch_bounds__(256) void scatter_dense_kernel(const float* __restrict__ pos,
                                                            const float* __restrict__ vel,
                                                            const float* __restrict__ mass,
                                                            const unsigned short* __restrict__ offs,
                                                            const unsigned int* __restrict__ binPrefix,
                                                            float4* __restrict__ rec,
                                                            int n, int chunk) {
    __shared__ unsigned int lof[NBINS];   // 16 KB
    int c = blockIdx.x, t = threadIdx.x;
    const unsigned short* row = offs + (size_t)c * NBINS;
    for (int j = t; j < NBINS; j += 256) lof[j] = (unsigned int)row[j] + binPrefix[j];
    __syncthreads();
    int s = c * chunk, e = min(n, s + chunk);
    for (int i = s + t; i < e; i += 256) {
        float rx = pos[3 * i + 0] * INV_CELL;
        float ry = pos[3 * i + 1] * INV_CELL;
        float rz = pos[3 * i + 2] * INV_CELL;
        int bin = ((((int)rx) >> 3) << 8) | ((((int)ry) >> 3) << 4) | (((int)rz) >> 3);
        unsigned int slot = atomicAdd(&lof[bin], 1u);
        size_t b2 = (size_t)slot * 2;
        rec[b2]     = make_float4(rx, ry, rz, __uint_as_float((unsigned int)i));
        rec[b2 + 1] = make_float4(vel[3 * i + 0], vel[3 * i + 1], vel[3 * i + 2], mass[i]);
    }
}

// ---------------- per-bin canonical permutation (no rec rewrite) ----------------
__global__ __launch_bounds__(256) void binperm_kernel(const unsigned int* __restrict__ binPrefix,
                                                      const float4* __restrict__ rec,
                                                      unsigned short* __restrict__ perm16,
                                                      unsigned short* __restrict__ bs16) {
    __shared__ unsigned short codeLi[STCAP];   // cell of physical slot k
    __shared__ unsigned int   oiArr[STCAP];    // orig idx of slot k
    __shared__ unsigned short dstA[STCAP];     // provisional slot, then final sorted pos
    __shared__ unsigned short permL[STCAP];    // provisional sorted pos -> k
    __shared__ unsigned int ccount[512];
    __shared__ unsigned int cstart[513];
    __shared__ unsigned int sh[256];

    int bin = blockIdx.x;
    int t = threadIdx.x;
    unsigned int base = binPrefix[bin];
    unsigned int cnt = binPrefix[bin + 1] - base;
    if (cnt > STCAP) cnt = STCAP;            // statistically never (8.8 sigma)
    ccount[t] = 0;
    ccount[t + 256] = 0;
    __syncthreads();

    for (unsigned int k = t; k < cnt; k += 256) {
        float4 a = rec[(size_t)(base + k) * 2];
        int li = ((((int)a.x) & 7) << 6) | ((((int)a.y) & 7) << 3) | (((int)a.z) & 7);
        codeLi[k] = (unsigned short)li;
        oiArr[k] = __float_as_uint(a.w);
        dstA[k] = (unsigned short)atomicAdd(&ccount[li], 1u);
    }
    __syncthreads();

    // exclusive scan of ccount[512] -> cstart (counts only => deterministic)
    unsigned int c0 = ccount[2 * t], c1 = ccount[2 * t + 1], s = c0 + c1;
    sh[t] = s;
    __syncthreads();
#pragma unroll
    for (int off = 1; off < 256; off <<= 1) {
        unsigned int add = (t >= off) ? sh[t - off] : 0u;
        __syncthreads();
        sh[t] += add;
        __syncthreads();
    }
    unsigned int pre = sh[t] - s;
    cstart[2 * t] = pre;
    cstart[2 * t + 1] = pre + c0;
    if (t == 255) cstart[512] = cnt;
    __syncthreads();

    // provisional inverse map
    for (unsigned int k = t; k < cnt; k += 256)
        permL[cstart[codeLi[k]] + dstA[k]] = (unsigned short)k;
    __syncthreads();

    // canonical rank within each cell by orig_idx (O(c^2), c ~ Poisson(0.58))
    for (int cell = t; cell < 512; cell += 256) {
        unsigned int c = ccount[cell];
        if (c == 0) continue;
        unsigned int s0 = cstart[cell];
        for (unsigned int a = 0; a < c; ++a) {
            unsigned int ka = permL[s0 + a];
            unsigned int oia = oiArr[ka];
            unsigned int r = 0;
            for (unsigned int b = 0; b < c; ++b)
                r += (oiArr[permL[s0 + b]] < oia) ? 1u : 0u;
            dstA[ka] = (unsigned short)(s0 + r);   // final sorted pos (unique)
        }
    }
    __syncthreads();

    // perm16[base + sorted] = physical local slot; bs16 = per-bin cell starts
    for (unsigned int k = t; k < cnt; k += 256)
        perm16[base + dstA[k]] = (unsigned short)k;
    for (int i = t; i < SPB; i += 256)
        bs16[(size_t)bin * SPB + i] = (unsigned short)cstart[i];
}

// ---------------- FUSED P2G + grid-vel + G2P: one wg per 8^3 block, no global grid ----------------
// Phase 1: RECORD-PARALLEL staging (span tables + binary search — proven form).
//   Transform once: A.z <- fz, A.w <- bits(oi | cz<<20).
// Phase 2: thread = (node column nx,ny ; z-segment of 3 nodes). Flattened
//   4-cell window loop, branchless z-weights, register accumulators; nodes
//   aliased onto lrecB after a barrier (LDS 29.3 KB => 5 wg/CU).
//   Summation order unchanged => deterministic.
// Phase 3: G2P per own cell (cell coords statically known).
__global__ __launch_bounds__(256) void fused_pg_kernel(const float4* __restrict__ rec,
                                                       const unsigned int* __restrict__ binPrefix,
                                                       const unsigned short* __restrict__ perm16,
                                                       const unsigned short* __restrict__ bs16,
                                                       float* __restrict__ out) {
    __shared__ float4 lrecA[FCAP];             // 11776 B
    __shared__ float4 lrecB[FCAP];             // 11776 B (nodes aliased here after phase 2)
    __shared__ unsigned short cst[100 * 11];   // 2200 B: staged start of cell d=k-1 per column
    __shared__ unsigned int   rSort[300];      // global sorted idx of span start
    __shared__ unsigned int   rBase[300];      // binPrefix of span's bin
    __shared__ unsigned short rDst[301];       // staged dst start (monotone)
    __shared__ unsigned int   sh[128];

    int wg = blockIdx.x;
    int Z = wg & 15, Y = (wg >> 4) & 15, X = wg >> 8;
    int t = threadIdx.x;

    // ---- phase 1a: per-column span discovery (threads 0..99) ----
    unsigned int cnt_[10];
    unsigned int sortA = 0, sortB = 0, sortC = 0;
    unsigned int baseA = 0, baseB = 0, baseC = 0;
    unsigned int colTotal = 0;
    if (t < 100) {
        int dxi = t / 10, dyi = t % 10;
        int cgx = 8 * X - 1 + dxi, cgy = 8 * Y - 1 + dyi;
#pragma unroll
        for (int k = 0; k < 10; ++k) cnt_[k] = 0;
        if ((unsigned)cgx < 128u && (unsigned)cgy < 128u) {
            int bX = cgx >> 3, bY = cgy >> 3;
            int li0 = ((cgx & 7) << 6) | ((cgy & 7) << 3);
            if (Z > 0) {   // cell d=-1 lives in bin Z-1 at lz=7
                int nb = (bX << 8) | (bY << 4) | (Z - 1);
                unsigned int bp = binPrefix[nb];
                const unsigned short* p = bs16 + (size_t)nb * SPB + li0 + 7;
                baseA = bp; sortA = bp + p[0];
                cnt_[0] = (unsigned int)p[1] - (unsigned int)p[0];
            }
            {              // cells d=0..7 in bin Z, lz=0..7 contiguous
                int nb = (bX << 8) | (bY << 4) | Z;
                unsigned int bp = binPrefix[nb];
                const unsigned short* p = bs16 + (size_t)nb * SPB + li0;
                unsigned int prev = p[0];
                baseB = bp; sortB = bp + prev;
#pragma unroll
                for (int k = 1; k <= 8; ++k) {
                    unsigned int cur = p[k];
                    cnt_[k] = cur - prev;
                    prev = cur;
                }
            }
            if (Z < 15) {  // cell d=8 in bin Z+1 at lz=0
                int nb = (bX << 8) | (bY << 4) | (Z + 1);
                unsigned int bp = binPrefix[nb];
                const unsigned short* p = bs16 + (size_t)nb * SPB + li0;
                baseC = bp; sortC = bp + p[0];
                cnt_[9] = (unsigned int)p[1] - (unsigned int)p[0];
            }
        }
#pragma unroll
        for (int k = 0; k < 10; ++k) colTotal += cnt_[k];
        sh[t] = colTotal;
    } else if (t < 128) {
        sh[t] = 0;
    }
    __syncthreads();
    for (int off = 1; off < 128; off <<= 1) {
        unsigned int add = 0;
        if (t < 128 && t >= off) add = sh[t - off];
        __syncthreads();
        if (t < 128) sh[t] += add;
        __syncthreads();
    }
    if (t < 100) {
        unsigned int run = sh[t] - colTotal;   // exclusive staged start of this column
        unsigned short c11[11];
#pragma unroll
        for (int k = 0; k < 10; ++k) {
            c11[k] = (unsigned short)min(run, (unsigned)FCAP);
            run += cnt_[k];
        }
        c11[10] = (unsigned short)min(run, (unsigned)FCAP);
#pragma unroll
        for (int k = 0; k < 11; ++k) cst[t * 11 + k] = c11[k];
        int r = t * 3;
        rSort[r]     = sortA;  rBase[r]     = baseA;  rDst[r]     = c11[0];
        rSort[r + 1] = sortB;  rBase[r + 1] = baseB;  rDst[r + 1] = c11[1];
        rSort[r + 2] = sortC;  rBase[r + 2] = baseC;  rDst[r + 2] = c11[9];
        if (t == 99) rDst[300] = c11[10];
    }
    __syncthreads();

    // ---- phase 1b: record-parallel gather via canonical perm + one-time transform ----
    unsigned int total = rDst[300];
    for (unsigned int q = t; q < total; q += 256) {
        int lo = 0, hi = 300;                 // largest r with rDst[r] <= q
        while (hi - lo > 1) {
            int mid = (lo + hi) >> 1;
            if ((unsigned int)rDst[mid] <= q) lo = mid; else hi = mid;
        }
        unsigned int sIdx = rSort[lo] + (q - rDst[lo]);
        size_t phys = (size_t)(rBase[lo] + perm16[sIdx]) * 2;
        float4 A = rec[phys];
        int cz = (int)A.z;                    // trunc == floor (A.z >= 0)
        float fzv = A.z - (float)cz;
        unsigned int oi = __float_as_uint(A.w);
        A.z = fzv;
        A.w = __uint_as_float(oi | ((unsigned int)cz << 20));
        lrecA[q] = A;
        lrecB[q] = rec[phys + 1];
    }
    __syncthreads();

    // ---- phase 2: flattened per-column-window node sums (registers) ----
    float4 A0 = make_float4(0.f, 0.f, 0.f, 0.f);
    float4 A1 = make_float4(0.f, 0.f, 0.f, 0.f);
    float4 A2 = make_float4(0.f, 0.f, 0.f, 0.f);
    int nb = 0;
    bool active = (t < 243);
    if (active) {
        int col9 = t / 3, s = t - 3 * col9;
        int nx = col9 / 9, ny = col9 % 9;
        int zbase = 8 * Z + 3 * s - 1;        // global z of window cell 0 (d=3s-1)
        nb = nx * 81 + ny * 9 + 3 * s;
#pragma unroll
        for (int i = 0; i < 2; ++i) {
            float cgx = (float)(8 * X - 1 + nx + i);
#pragma unroll
            for (int j = 0; j < 2; ++j) {
                float cgy = (float)(8 * Y - 1 + ny + j);
                const unsigned short* cc = cst + ((nx + i) * 10 + (ny + j)) * 11 + 3 * s;
                unsigned int k0 = cc[0], k4 = cc[4];
                for (unsigned int k = k0; k < k4; ++k) {
                    float4 a = lrecA[k];
                    float4 b = lrecB[k];
                    float fx = a.x - cgx, fy = a.y - cgy;
                    float wx = i ? 1.0f - fx : fx;
                    float wy = j ? 1.0f - fy : fy;
                    float fz = a.z;                             // precomputed
                    float omfz = 1.0f - fz;
                    int d = (int)(__float_as_uint(a.w) >> 20) - zbase;   // 0..3
                    float wm = wx * wy * b.w;
                    float wz0 = (d == 0) ? fz : ((d == 1) ? omfz : 0.0f);
                    float wz1 = (d == 1) ? fz : ((d == 2) ? omfz : 0.0f);
                    float wz2 = (d == 2) ? fz : ((d == 3) ? omfz : 0.0f);
                    float w0 = wm * wz0, w1 = wm * wz1, w2 = wm * wz2;
                    A0.x += w0; A0.y += w0 * b.x; A0.z += w0 * b.y; A0.w += w0 * b.z;
                    A1.x += w1; A1.y += w1 * b.x; A1.z += w1 * b.y; A1.w += w1 * b.z;
                    A2.x += w2; A2.y += w2 * b.x; A2.z += w2 * b.y; A2.w += w2 * b.z;
                }
            }
        }
    }
    __syncthreads();   // all lrecB reads complete -> safe to alias nodes onto it

    float* nodeX = (float*)lrecB;          // 729 floats
    float* nodeY = nodeX + 729;
    float* nodeZ = nodeY + 729;            // 8748 B total, fits in lrecB's 11776 B
    if (active) {
        float inv0 = 1.0f / fmaxf(A0.x, EPS);
        nodeX[nb] = A0.y * inv0; nodeY[nb] = A0.z * inv0; nodeZ[nb] = A0.w * inv0;
        float inv1 = 1.0f / fmaxf(A1.x, EPS);
        nodeX[nb + 1] = A1.y * inv1; nodeY[nb + 1] = A1.z * inv1; nodeZ[nb + 1] = A1.w * inv1;
        float inv2 = 1.0f / fmaxf(A2.x, EPS);
        nodeX[nb + 2] = A2.y * inv2; nodeY[nb + 2] = A2.z * inv2; nodeZ[nb + 2] = A2.w * inv2;
    }
    __syncthreads();

    // ---- phase 3: G2P per own cell from LDS nodes (cell coords known) ----
    for (int cell = t; cell < 512; cell += 256) {
        int lx = cell >> 6, ly = (cell >> 3) & 7, lz = cell & 7;
        const unsigned short* cc = cst + ((lx + 1) * 10 + (ly + 1)) * 11 + (lz + 1);
        unsigned int s0 = cc[0], e0 = cc[1];
        float bx = (float)(8 * X + lx), by = (float)(8 * Y + ly);
        int nb3 = lx * 81 + ly * 9 + lz;
        for (unsigned int k = s0; k < e0; ++k) {
            float4 a = lrecA[k];
            float fx = a.x - bx, fy = a.y - by, fz = a.z;   // fz precomputed
            float wxa[2] = {1.0f - fx, fx};
            float wya[2] = {1.0f - fy, fy};
            float wza[2] = {1.0f - fz, fz};
            float ox = 0.f, oy = 0.f, oz = 0.f;
#pragma unroll
            for (int i = 0; i < 2; ++i) {
#pragma unroll
                for (int j = 0; j < 2; ++j) {
#pragma unroll
                    for (int l = 0; l < 2; ++l) {
                        int ni = nb3 + i * 81 + j * 9 + l;
                        float w = wxa[i] * wya[j] * wza[l];
                        ox += w * nodeX[ni];
                        oy += w * nodeY[ni];
                        oz += w * nodeZ[ni];
                    }
                }
            }
            unsigned int oi = __float_as_uint(a.w) & 0xFFFFFu;
            out[3 * (size_t)oi + 0] = ox;
            out[3 * (size_t)oi + 1] = oy;
            out[3 * (size_t)oi + 2] = oz;
        }
    }
}

// ---------------- fallback (atomic path, needs only 32 MiB) ----------------
__global__ __launch_bounds__(256) void p2g_atomic_kernel(const float* __restrict__ pos,
                                                         const float* __restrict__ vel,
                                                         const float* __restrict__ mass,
                                                         float4* __restrict__ grid, int n) {
    int i = blockIdx.x * blockDim.x + threadIdx.x;
    if (i >= n) return;
    float rx = pos[3 * i] * INV_CELL, ry = pos[3 * i + 1] * INV_CELL, rz = pos[3 * i + 2] * INV_CELL;
    int bx = (int)floorf(rx), by = (int)floorf(ry), bz = (int)floorf(rz);
    float wx[2] = {1.0f - (rx - bx), rx - bx}, wy[2] = {1.0f - (ry - by), ry - by}, wz[2] = {1.0f - (rz - bz), rz - bz};
    float m = mass[i], vx = vel[3 * i], vy = vel[3 * i + 1], vz = vel[3 * i + 2];
#pragma unroll
    for (int a = 0; a < 2; ++a)
#pragma unroll
        for (int b = 0; b < 2; ++b)
#pragma unroll
            for (int c = 0; c < 2; ++c) {
                float w = wx[a] * wy[b] * wz[c] * m;
                int idx = (((((bx + a) & GMASK) << 7) | ((by + b) & GMASK)) << 7) | ((bz + c) & GMASK);
                float* cell = (float*)(grid + idx);
                atomicAdd(cell + 0, w);
                atomicAdd(cell + 1, w * vx);
                atomicAdd(cell + 2, w * vy);
                atomicAdd(cell + 3, w * vz);
            }
}

__global__ __launch_bounds__(256) void gridvel_kernel(float4* __restrict__ grid) {
    int i = blockIdx.x * blockDim.x + threadIdx.x;
    if (i >= NCELLS) return;
    float4 g = grid[i];
    float inv = 1.0f / fmaxf(g.x, EPS);
    grid[i] = make_float4(g.y * inv, g.z * inv, g.w * inv, 0.0f);
}

__global__ __launch_bounds__(256) void g2p_plain_kernel(const float* __restrict__ pos,
                                                        const float4* __restrict__ grid,
                                                        float* __restrict__ out, int n) {
    int i = blockIdx.x * blockDim.x + threadIdx.x;
    if (i >= n) return;
    float rx = pos[3 * i] * INV_CELL, ry = pos[3 * i + 1] * INV_CELL, rz = pos[3 * i + 2] * INV_CELL;
    int bx = (int)floorf(rx), by = (int)floorf(ry), bz = (int)floorf(rz);
    float wx[2] = {1.0f - (rx - bx), rx - bx}, wy[2] = {1.0f - (ry - by), ry - by}, wz[2] = {1.0f - (rz - bz), rz - bz};
    float ox = 0, oy = 0, oz = 0;
#pragma unroll
    for (int a = 0; a < 2; ++a)
#pragma unroll
        for (int b = 0; b < 2; ++b)
#pragma unroll
            for (int c = 0; c < 2; ++c) {
                float w = wx[a] * wy[b] * wz[c];
                int idx = (((((bx + a) & GMASK) << 7) | ((by + b) & GMASK)) << 7) | ((bz + c) & GMASK);
                float4 g = grid[idx];
                ox += w * g.x; oy += w * g.y; oz += w * g.z;
            }
    out[3 * i] = ox; out[3 * i + 1] = oy; out[3 * i + 2] = oz;
}

extern "C" void kernel_launch(void* const* d_in, const int* in_sizes, int n_in,
                              void* d_out, int out_size, void* d_ws, size_t ws_size,
                              hipStream_t stream) {
    const float* pos  = (const float*)d_in[0];
    const float* vel  = (const float*)d_in[1];
    const float* mass = (const float*)d_in[2];
    float* out = (float*)d_out;
    int n = in_sizes[2];

    char* ws = (char*)d_ws;
    size_t off = 0;
    float4* rec  = (float4*)(ws + off);                    off += (size_t)n * 32;               // 30.5 MiB
    unsigned int* binTotal  = (unsigned int*)(ws + off);   off += (size_t)NBINS * 4;
    unsigned int* binPrefix = (unsigned int*)(ws + off);   off += (size_t)(NBINS + 8) * 4;
    unsigned short* cnt     = (unsigned short*)(ws + off); off += (size_t)NCHUNK * NBINS * 2;   // 2 MiB
    unsigned short* offs    = (unsigned short*)(ws + off); off += (size_t)NCHUNK * NBINS * 2;   // 2 MiB
    unsigned short* bs16    = (unsigned short*)(ws + off); off += (size_t)NBINS * SPB * 2;      // 4.2 MiB
    unsigned short* perm16  = (unsigned short*)(ws + off); off += (size_t)n * 2;                // 2 MiB
    size_t need = off;

    int pblocks = (n + 255) / 256;
    int chunk = (n + NCHUNK - 1) / NCHUNK;

    if (ws_size < need) {
        float4* g0 = (float4*)d_ws;   // fallback path owns the whole workspace
        hipMemsetAsync(d_ws, 0, (size_t)NCELLS * 16, stream);
        p2g_atomic_kernel<<<pblocks, 256, 0, stream>>>(pos, vel, mass, g0, n);
        gridvel_kernel<<<NCELLS / 256, 256, 0, stream>>>(g0);
        g2p_plain_kernel<<<pblocks, 256, 0, stream>>>(pos, g0, out, n);
        return;
    }

    hist_kernel<<<NCHUNK, 256, 0, stream>>>(pos, cnt, n, chunk);
    scan_cols_kernel<<<NBINS / 256, 256, 0, stream>>>(cnt, offs, binTotal);
    scan_bins_kernel<<<1, 256, 0, stream>>>(binTotal, binPrefix, n);
    scatter_dense_kernel<<<NCHUNK, 256, 0, stream>>>(pos, vel, mass, offs, binPrefix, rec, n, chunk);
    binperm_kernel<<<NBINS, 256, 0, stream>>>(binPrefix, rec, perm16, bs16);
    fused_pg_kernel<<<NBINS, 256, 0, stream>>>(rec, binPrefix, perm16, bs16, out);
}